// Round 8
// baseline (391.257 us; speedup 1.0000x reference)
//
#include <hip/hip_runtime.h>
#include <float.h>

#define NN 50000
#define NE 800000
#define FD 64
#define NG 64
#define SCAN_B 256
#define NBLK ((NN + SCAN_B - 1) / SCAN_B)   // 196
#define GEMM_BLOCKS 512
#define FILL_BLOCKS 1024
#define RANGE (NN / 8)                      // 6250 dst nodes per assumed-XCD group

typedef __attribute__((ext_vector_type(8))) short short8;
typedef __attribute__((ext_vector_type(8))) float float8;
typedef __attribute__((ext_vector_type(4))) float f32x4;

// ---------- bf16 helpers (RNE) ----------
__device__ inline unsigned short f2bf(float f) {
    unsigned u = __float_as_uint(f);
    u += 0x7fffu + ((u >> 16) & 1u);
    return (unsigned short)(u >> 16);
}
__device__ inline float bf2f(unsigned short h) {
    return __uint_as_float(((unsigned)h) << 16);
}

// ---------- monotonic float<->uint encoding for atomic max ----------
__device__ inline unsigned encf(float f) {
    unsigned u = __float_as_uint(f);
    return (u & 0x80000000u) ? ~u : (u | 0x80000000u);
}
__device__ inline float decf(unsigned e) {
    unsigned u = (e & 0x80000000u) ? (e ^ 0x80000000u) : ~e;
    return __uint_as_float(u);
}

// ---------- init: cnt = 0, gmax = enc(-inf) ----------
__global__ void k_init(int* __restrict__ cnt, unsigned* __restrict__ gmax) {
    int i = blockIdx.x * blockDim.x + threadIdx.x;
    if (i < NN) cnt[i] = 0;
    if (i < NG * FD) gmax[i] = encf(-FLT_MAX);
}

// ---------- histogram, dst-range partitioned by assumed XCD (bid&7) ----------
__global__ __launch_bounds__(256) void k_cnt_p(const int* __restrict__ dst,
                                               int* __restrict__ cnt) {
    int g  = blockIdx.x & 7;
    int r  = blockIdx.x >> 3;
    int lo = g * RANGE, hi = lo + RANGE;
    int nthr = ((int)gridDim.x >> 3) * 256;
    for (int e = r * 256 + threadIdx.x; e < NE; e += nthr) {
        int d = dst[e];
        if (d >= lo && d < hi) atomicAdd(&cnt[d], 1);
    }
}

// ---------- scan1 (+ dis folded in) ----------
__global__ void k_scan1(const int* __restrict__ cnt, int* __restrict__ rp,
                        int* __restrict__ bsum, float* __restrict__ dis) {
    __shared__ int tmp[SCAN_B];
    int b = blockIdx.x, t = threadIdx.x;
    int i = b * SCAN_B + t;
    int v = (i < NN) ? cnt[i] : 0;
    if (i < NN) dis[i] = rsqrtf((float)v + 1.0f);   // +1 self loop
    tmp[t] = v;
    __syncthreads();
    for (int off = 1; off < SCAN_B; off <<= 1) {
        int add = (t >= off) ? tmp[t - off] : 0;
        __syncthreads();
        tmp[t] += add;
        __syncthreads();
    }
    if (i < NN) rp[i] = tmp[t] - v;
    if (t == SCAN_B - 1) bsum[b] = tmp[t];
}

// ---------- fused scan2+scan3: each block computes its own bsum prefix ----------
__global__ __launch_bounds__(256) void k_scan23(int* __restrict__ rp,
                                                const int* __restrict__ bsum,
                                                int* __restrict__ cnt) {
    __shared__ int ws[4];
    int b = blockIdx.x, t = threadIdx.x;
    int v = (t < b) ? bsum[t] : 0;            // t < b <= 195 -> in bounds
#pragma unroll
    for (int m = 1; m < 64; m <<= 1) v += __shfl_xor(v, m);
    if ((t & 63) == 0) ws[t >> 6] = v;
    __syncthreads();
    int pre = ws[0] + ws[1] + ws[2] + ws[3];
    int i = b * 256 + t;
    if (i < NN) {
        rp[i] += pre;
        cnt[i] = 0;                           // becomes fill cursor
    }
    if (i == 0) rp[NN] = NE;
}

// ---------- MFMA GEMM body: HsB[r,:] = bf16( dis[r] * (A[r,:] @ W) ) ----------
// SPLIT_A=1: A f32 (hi/lo split, 3 MFMAs). SPLIT_A=0: A bf16 (2 MFMAs).
template<int SPLIT_A>
__device__ __forceinline__ void gemm_body(const float* __restrict__ Af,
                                          const unsigned short* __restrict__ Ab,
                                          const float* __restrict__ W,
                                          const float* __restrict__ dis,
                                          unsigned short* __restrict__ HsB,
                                          unsigned short* WtHi, unsigned short* WtLo,
                                          int bid, int nblk) {
    for (int i = threadIdx.x; i < 4096; i += 256) {
        int k = i >> 6, n = i & 63;
        float w = W[i];                        // W[k][n]
        unsigned short hi = f2bf(w);
        WtHi[n * 64 + k] = hi;
        WtLo[n * 64 + k] = f2bf(w - bf2f(hi));
    }
    __syncthreads();
    int lane = threadIdx.x & 63;
    int m  = lane & 15;    // A-row / D-col
    int kg = lane >> 4;    // k group
    short8 bh[4][2], bl[4][2];
#pragma unroll
    for (int t = 0; t < 4; ++t)
#pragma unroll
        for (int c = 0; c < 2; ++c) {
            int n  = 16 * t + m;
            int k0 = 32 * c + kg * 8;
            bh[t][c] = *(const short8*)&WtHi[n * 64 + k0];
            bl[t][c] = *(const short8*)&WtLo[n * 64 + k0];
        }
    int wid = (bid * 256 + (int)threadIdx.x) >> 6;
    int nw  = nblk * 4;
    for (int tile = wid; tile < NN / 16; tile += nw) {   // NN = 16*3125 exactly
        int r0 = tile * 16;
        f32x4 z = {0.f, 0.f, 0.f, 0.f};
        f32x4 acc0 = z, acc1 = z, acc2 = z, acc3 = z;
#pragma unroll
        for (int c = 0; c < 2; ++c) {
            short8 ah, al;
            if (SPLIT_A) {
                float8 xv = *(const float8*)(Af + (size_t)(r0 + m) * FD + 32 * c + kg * 8);
#pragma unroll
                for (int j = 0; j < 8; ++j) {
                    unsigned short hi = f2bf(xv[j]);
                    ah[j] = (short)hi;
                    al[j] = (short)f2bf(xv[j] - bf2f(hi));
                }
            } else {
                ah = *(const short8*)(Ab + (size_t)(r0 + m) * FD + 32 * c + kg * 8);
            }
            acc0 = __builtin_amdgcn_mfma_f32_16x16x32_bf16(ah, bh[0][c], acc0, 0, 0, 0);
            acc0 = __builtin_amdgcn_mfma_f32_16x16x32_bf16(ah, bl[0][c], acc0, 0, 0, 0);
            acc1 = __builtin_amdgcn_mfma_f32_16x16x32_bf16(ah, bh[1][c], acc1, 0, 0, 0);
            acc1 = __builtin_amdgcn_mfma_f32_16x16x32_bf16(ah, bl[1][c], acc1, 0, 0, 0);
            acc2 = __builtin_amdgcn_mfma_f32_16x16x32_bf16(ah, bh[2][c], acc2, 0, 0, 0);
            acc2 = __builtin_amdgcn_mfma_f32_16x16x32_bf16(ah, bl[2][c], acc2, 0, 0, 0);
            acc3 = __builtin_amdgcn_mfma_f32_16x16x32_bf16(ah, bh[3][c], acc3, 0, 0, 0);
            acc3 = __builtin_amdgcn_mfma_f32_16x16x32_bf16(ah, bl[3][c], acc3, 0, 0, 0);
            if (SPLIT_A) {
                acc0 = __builtin_amdgcn_mfma_f32_16x16x32_bf16(al, bh[0][c], acc0, 0, 0, 0);
                acc1 = __builtin_amdgcn_mfma_f32_16x16x32_bf16(al, bh[1][c], acc1, 0, 0, 0);
                acc2 = __builtin_amdgcn_mfma_f32_16x16x32_bf16(al, bh[2][c], acc2, 0, 0, 0);
                acc3 = __builtin_amdgcn_mfma_f32_16x16x32_bf16(al, bh[3][c], acc3, 0, 0, 0);
            }
        }
#pragma unroll
        for (int r = 0; r < 4; ++r) {
            int row = r0 + kg * 4 + r;
            float dd = dis[row];
            size_t base = (size_t)row * FD;
            HsB[base + 16 * 0 + m] = f2bf(dd * acc0[r]);
            HsB[base + 16 * 1 + m] = f2bf(dd * acc1[r]);
            HsB[base + 16 * 2 + m] = f2bf(dd * acc2[r]);
            HsB[base + 16 * 3 + m] = f2bf(dd * acc3[r]);
        }
    }
}

// ---------- fused: gemm1 (blocks [0,512)) || XCD-partitioned CSR fill ----------
__global__ __launch_bounds__(256) void k_fill_gemm(const int* __restrict__ src,
                                                   const int* __restrict__ dst,
                                                   const int* __restrict__ rp,
                                                   int* __restrict__ cur,
                                                   int* __restrict__ esrc,
                                                   const float* __restrict__ X,
                                                   const float* __restrict__ W,
                                                   const float* __restrict__ dis,
                                                   unsigned short* __restrict__ HsB) {
    __shared__ unsigned short WtHi[4096];
    __shared__ unsigned short WtLo[4096];
    if (blockIdx.x < GEMM_BLOCKS) {
        gemm_body<1>(X, nullptr, W, dis, HsB, WtHi, WtLo, blockIdx.x, GEMM_BLOCKS);
    } else {
        int b  = blockIdx.x - GEMM_BLOCKS;   // GEMM_BLOCKS%8==0 keeps bid&7 alignment
        int g  = b & 7;
        int r  = b >> 3;
        int lo = g * RANGE, hi = lo + RANGE;
        int nthr = (FILL_BLOCKS >> 3) * 256;
        for (int e = r * 256 + threadIdx.x; e < NE; e += nthr) {
            int d = dst[e];
            if (d >= lo && d < hi) {
                int p = rp[d] + atomicAdd(&cur[d], 1);
                esrc[p] = src[e];
            }
        }
    }
}

__global__ __launch_bounds__(256) void k_gemm2(const unsigned short* __restrict__ Ab,
                                               const float* __restrict__ W,
                                               const float* __restrict__ dis,
                                               unsigned short* __restrict__ HsB) {
    __shared__ unsigned short WtHi[4096];
    __shared__ unsigned short WtLo[4096];
    gemm_body<0>(nullptr, Ab, W, dis, HsB, WtHi, WtLo, blockIdx.x, GEMM_BLOCKS);
}

// ---------- gather: one wave per node, 8 edge-slots x 8-feat lanes ----------
// Per row-load instruction: 8 lanes x 16 B = one 128 B row; wave covers 8 edges.
// Item t: t==0 -> self row d, t in [1,deg] -> esrc[beg+t-1]; invalid -> weight 0.
// After loop: butterfly over slots (shfl_xor 8,16,32).
// MODE 0: Obf[d,:] = bf16(relu(dis[d]*sum + b))   MODE 1: atomicMax into gmax.
template<int MODE>
__global__ __launch_bounds__(256) void k_gather8(const int* __restrict__ rp,
                                                 const int* __restrict__ esrc,
                                                 const float* __restrict__ dis,
                                                 const unsigned short* __restrict__ HsB,
                                                 const float* __restrict__ bias,
                                                 unsigned short* __restrict__ Obf,
                                                 const int* __restrict__ batch,
                                                 unsigned* __restrict__ gmax) {
    int gtid  = blockIdx.x * blockDim.x + threadIdx.x;
    int wave  = gtid >> 6;
    int lane  = threadIdx.x & 63;
    int slot  = lane >> 3;     // edge slot 0..7
    int fg    = lane & 7;      // feature group: feats [fg*8, fg*8+8)
    int nwave = (gridDim.x * blockDim.x) >> 6;
    float bb[8];
#pragma unroll
    for (int i = 0; i < 8; ++i) bb[i] = bias[fg * 8 + i];
    for (int d = wave; d < NN; d += nwave) {
        int beg = rp[d], end = rp[d + 1];
        int deg = end - beg;
        float acc[8];
#pragma unroll
        for (int i = 0; i < 8; ++i) acc[i] = 0.f;
#pragma unroll
        for (int k = 0; k < 4; ++k) {
            if (8 * k <= deg) {                    // wave-uniform guard
                int t   = 8 * k + slot;
                int idx = beg + t - 1;
                idx = idx < 0 ? 0 : idx;
                idx = idx > NE - 1 ? NE - 1 : idx;
                int sv = esrc[idx];
                sv = (t == 0) ? d : sv;
                float w = (t <= deg) ? 1.0f : 0.0f;
                const short8 r = *(const short8*)(HsB + (size_t)sv * FD + fg * 8);
#pragma unroll
                for (int i = 0; i < 8; ++i)
                    acc[i] = fmaf(w, bf2f((unsigned short)r[i]), acc[i]);
            }
        }
        if (deg >= 32) {                           // rare tail (Poisson(16))
            for (int idx = beg + 31 + slot; idx < end; idx += 8) {
                int sv = esrc[idx];
                const short8 r = *(const short8*)(HsB + (size_t)sv * FD + fg * 8);
#pragma unroll
                for (int i = 0; i < 8; ++i)
                    acc[i] += bf2f((unsigned short)r[i]);
            }
        }
#pragma unroll
        for (int m = 8; m < 64; m <<= 1)
#pragma unroll
            for (int i = 0; i < 8; ++i)
                acc[i] += __shfl_xor(acc[i], m);
        float dd = dis[d];
        if (MODE == 0) {
            if (slot == 0) {
                short8 o;
#pragma unroll
                for (int i = 0; i < 8; ++i) {
                    float v = fmaf(dd, acc[i], bb[i]);
                    o[i] = (short)f2bf(fmaxf(v, 0.0f));
                }
                *(short8*)(Obf + (size_t)d * FD + fg * 8) = o;
            }
        } else {
            if (slot == 0) {
                int g = batch[d];
#pragma unroll
                for (int i = 0; i < 8; ++i) {
                    float v = fmaf(dd, acc[i], bb[i]);
                    atomicMax(&gmax[g * FD + fg * 8 + i], encf(v));
                }
            }
        }
    }
}

// ---------- final: out[g,c] = sum_f gmax[g,f] * Wlin[f,c] + blin[c] ----------
__global__ __launch_bounds__(128) void k_final(const unsigned* __restrict__ gmax,
                                               const float* __restrict__ Wlin,
                                               const float* __restrict__ blin,
                                               float* __restrict__ out) {
    __shared__ float G[NG * FD];
    for (int i = threadIdx.x; i < NG * FD; i += 128) G[i] = decf(gmax[i]);
    __syncthreads();
    int t = threadIdx.x;
    int g = t >> 1, c = t & 1;
    float acc = blin[c];
#pragma unroll
    for (int f = 0; f < 64; ++f) acc = fmaf(G[g * 64 + f], Wlin[f * 2 + c], acc);
    out[g * 2 + c] = acc;
}

extern "C" void kernel_launch(void* const* d_in, const int* in_sizes, int n_in,
                              void* d_out, int out_size, void* d_ws, size_t ws_size,
                              hipStream_t stream) {
    const float* x     = (const float*)d_in[0];
    const int*   eidx  = (const int*)d_in[1];
    const int*   batch = (const int*)d_in[2];
    const float* W1    = (const float*)d_in[3];
    const float* b1    = (const float*)d_in[4];
    const float* W2    = (const float*)d_in[5];
    const float* b2    = (const float*)d_in[6];
    const float* Wlin  = (const float*)d_in[7];
    const float* blin  = (const float*)d_in[8];
    float* out = (float*)d_out;

    const int* src = eidx;
    const int* dst = eidx + NE;

    char* ws = (char*)d_ws;
    size_t off = 0;
    auto alloc = [&](size_t bytes) { char* p = ws + off; off += (bytes + 255) & ~size_t(255); return p; };
    int*            cnt  = (int*)alloc(NN * 4);
    float*          dis  = (float*)alloc(NN * 4);
    int*            rp   = (int*)alloc((NN + 1) * 4);
    int*            bsum = (int*)alloc(NBLK * 4);
    int*            esrc = (int*)alloc(NE * 4);                          // 3.2 MB
    unsigned*       gmax = (unsigned*)alloc(NG * FD * 4);
    unsigned short* HsB  = (unsigned short*)alloc((size_t)NN * FD * 2);  // 6.4 MB
    unsigned short* Obf  = (unsigned short*)alloc((size_t)NN * FD * 2);  // 6.4 MB

    const int B = 256;
    const int gN = (NN + B - 1) / B;
    const int gatherBlocks = 2048;   // 8192 waves, ~6 nodes each

    // ---- CSR build + norm ----
    k_init<<<gN, B, 0, stream>>>(cnt, gmax);
    k_cnt_p<<<1024, B, 0, stream>>>(dst, cnt);
    k_scan1<<<NBLK, SCAN_B, 0, stream>>>(cnt, rp, bsum, dis);
    k_scan23<<<NBLK, 256, 0, stream>>>(rp, bsum, cnt);

    // ---- fill || layer-1 GEMM (independent) ----
    k_fill_gemm<<<GEMM_BLOCKS + FILL_BLOCKS, B, 0, stream>>>(src, dst, rp, cnt, esrc,
                                                             x, W1, dis, HsB);

    // ---- layer 1 gather: Obf = bf16(relu(dis*gather(HsB) + b1)) ----
    k_gather8<0><<<gatherBlocks, B, 0, stream>>>(rp, esrc, dis, HsB, b1, Obf, batch, gmax);

    // ---- layer 2: HsB = bf16(dis * (Obf @ W2)) ; gmax = segmax(...) ----
    k_gemm2<<<GEMM_BLOCKS, B, 0, stream>>>(Obf, W2, dis, HsB);
    k_gather8<1><<<gatherBlocks, B, 0, stream>>>(rp, esrc, dis, HsB, b2, nullptr, batch, gmax);

    // ---- head ----
    k_final<<<1, 128, 0, stream>>>(gmax, Wlin, blin, out);
}

// Round 9
// 221.862 us; speedup vs baseline: 1.7635x; 1.7635x over previous
//
#include <hip/hip_runtime.h>
#include <float.h>

#define NN 50000
#define NE 800000
#define FD 64
#define NG 64
#define SCAN_B 256
#define NBLK ((NN + SCAN_B - 1) / SCAN_B)   // 196
#define GEMM_BLOCKS 512
#define FILL_BLOCKS 1024
#define RANGE (NN / 8)                      // 6250 dst nodes per assumed-XCD group

typedef __attribute__((ext_vector_type(8))) short short8;
typedef __attribute__((ext_vector_type(8))) float float8;
typedef __attribute__((ext_vector_type(4))) float f32x4;

// ---------- bf16 helpers (RNE) ----------
__device__ inline unsigned short f2bf(float f) {
    unsigned u = __float_as_uint(f);
    u += 0x7fffu + ((u >> 16) & 1u);
    return (unsigned short)(u >> 16);
}
__device__ inline float bf2f(unsigned short h) {
    return __uint_as_float(((unsigned)h) << 16);
}

// ---------- monotonic float<->uint encoding for atomic max ----------
__device__ inline unsigned encf(float f) {
    unsigned u = __float_as_uint(f);
    return (u & 0x80000000u) ? ~u : (u | 0x80000000u);
}
__device__ inline float decf(unsigned e) {
    unsigned u = (e & 0x80000000u) ? (e ^ 0x80000000u) : ~e;
    return __uint_as_float(u);
}

// ---------- init: cnt = 0, gmax = enc(-inf) ----------
__global__ void k_init(int* __restrict__ cnt, unsigned* __restrict__ gmax) {
    int i = blockIdx.x * blockDim.x + threadIdx.x;
    if (i < NN) cnt[i] = 0;
    if (i < NG * FD) gmax[i] = encf(-FLT_MAX);
}

// ---------- histogram, dst-range partitioned by assumed XCD (bid&7) ----------
__global__ __launch_bounds__(256) void k_cnt_p(const int* __restrict__ dst,
                                               int* __restrict__ cnt) {
    int g  = blockIdx.x & 7;
    int r  = blockIdx.x >> 3;
    int lo = g * RANGE, hi = lo + RANGE;
    int nthr = ((int)gridDim.x >> 3) * 256;
    for (int e = r * 256 + threadIdx.x; e < NE; e += nthr) {
        int d = dst[e];
        if (d >= lo && d < hi) atomicAdd(&cnt[d], 1);
    }
}

// ---------- scan1 (+ dis folded in) ----------
__global__ void k_scan1(const int* __restrict__ cnt, int* __restrict__ rp,
                        int* __restrict__ bsum, float* __restrict__ dis) {
    __shared__ int tmp[SCAN_B];
    int b = blockIdx.x, t = threadIdx.x;
    int i = b * SCAN_B + t;
    int v = (i < NN) ? cnt[i] : 0;
    if (i < NN) dis[i] = rsqrtf((float)v + 1.0f);   // +1 self loop
    tmp[t] = v;
    __syncthreads();
    for (int off = 1; off < SCAN_B; off <<= 1) {
        int add = (t >= off) ? tmp[t - off] : 0;
        __syncthreads();
        tmp[t] += add;
        __syncthreads();
    }
    if (i < NN) rp[i] = tmp[t] - v;
    if (t == SCAN_B - 1) bsum[b] = tmp[t];
}

// ---------- fused scan2+scan3: each block computes its own bsum prefix ----------
__global__ __launch_bounds__(256) void k_scan23(int* __restrict__ rp,
                                                const int* __restrict__ bsum,
                                                int* __restrict__ cnt) {
    __shared__ int ws[4];
    int b = blockIdx.x, t = threadIdx.x;
    int v = (t < b) ? bsum[t] : 0;            // t < b <= 195 -> in bounds
#pragma unroll
    for (int m = 1; m < 64; m <<= 1) v += __shfl_xor(v, m);
    if ((t & 63) == 0) ws[t >> 6] = v;
    __syncthreads();
    int pre = ws[0] + ws[1] + ws[2] + ws[3];
    int i = b * 256 + t;
    if (i < NN) {
        rp[i] += pre;
        cnt[i] = 0;                           // becomes fill cursor
    }
    if (i == 0) rp[NN] = NE;
}

// ---------- MFMA GEMM body: HsB[r,:] = bf16( dis[r] * (A[r,:] @ W) ) ----------
// SPLIT_A=1: A f32 (hi/lo split, 3 MFMAs). SPLIT_A=0: A bf16 (2 MFMAs).
template<int SPLIT_A>
__device__ __forceinline__ void gemm_body(const float* __restrict__ Af,
                                          const unsigned short* __restrict__ Ab,
                                          const float* __restrict__ W,
                                          const float* __restrict__ dis,
                                          unsigned short* __restrict__ HsB,
                                          unsigned short* WtHi, unsigned short* WtLo,
                                          int bid, int nblk) {
    for (int i = threadIdx.x; i < 4096; i += 256) {
        int k = i >> 6, n = i & 63;
        float w = W[i];                        // W[k][n]
        unsigned short hi = f2bf(w);
        WtHi[n * 64 + k] = hi;
        WtLo[n * 64 + k] = f2bf(w - bf2f(hi));
    }
    __syncthreads();
    int lane = threadIdx.x & 63;
    int m  = lane & 15;    // A-row / D-col
    int kg = lane >> 4;    // k group
    short8 bh[4][2], bl[4][2];
#pragma unroll
    for (int t = 0; t < 4; ++t)
#pragma unroll
        for (int c = 0; c < 2; ++c) {
            int n  = 16 * t + m;
            int k0 = 32 * c + kg * 8;
            bh[t][c] = *(const short8*)&WtHi[n * 64 + k0];
            bl[t][c] = *(const short8*)&WtLo[n * 64 + k0];
        }
    int wid = (bid * 256 + (int)threadIdx.x) >> 6;
    int nw  = nblk * 4;
    for (int tile = wid; tile < NN / 16; tile += nw) {   // NN = 16*3125 exactly
        int r0 = tile * 16;
        f32x4 z = {0.f, 0.f, 0.f, 0.f};
        f32x4 acc0 = z, acc1 = z, acc2 = z, acc3 = z;
#pragma unroll
        for (int c = 0; c < 2; ++c) {
            short8 ah, al;
            if (SPLIT_A) {
                float8 xv = *(const float8*)(Af + (size_t)(r0 + m) * FD + 32 * c + kg * 8);
#pragma unroll
                for (int j = 0; j < 8; ++j) {
                    unsigned short hi = f2bf(xv[j]);
                    ah[j] = (short)hi;
                    al[j] = (short)f2bf(xv[j] - bf2f(hi));
                }
            } else {
                ah = *(const short8*)(Ab + (size_t)(r0 + m) * FD + 32 * c + kg * 8);
            }
            acc0 = __builtin_amdgcn_mfma_f32_16x16x32_bf16(ah, bh[0][c], acc0, 0, 0, 0);
            acc0 = __builtin_amdgcn_mfma_f32_16x16x32_bf16(ah, bl[0][c], acc0, 0, 0, 0);
            acc1 = __builtin_amdgcn_mfma_f32_16x16x32_bf16(ah, bh[1][c], acc1, 0, 0, 0);
            acc1 = __builtin_amdgcn_mfma_f32_16x16x32_bf16(ah, bl[1][c], acc1, 0, 0, 0);
            acc2 = __builtin_amdgcn_mfma_f32_16x16x32_bf16(ah, bh[2][c], acc2, 0, 0, 0);
            acc2 = __builtin_amdgcn_mfma_f32_16x16x32_bf16(ah, bl[2][c], acc2, 0, 0, 0);
            acc3 = __builtin_amdgcn_mfma_f32_16x16x32_bf16(ah, bh[3][c], acc3, 0, 0, 0);
            acc3 = __builtin_amdgcn_mfma_f32_16x16x32_bf16(ah, bl[3][c], acc3, 0, 0, 0);
            if (SPLIT_A) {
                acc0 = __builtin_amdgcn_mfma_f32_16x16x32_bf16(al, bh[0][c], acc0, 0, 0, 0);
                acc1 = __builtin_amdgcn_mfma_f32_16x16x32_bf16(al, bh[1][c], acc1, 0, 0, 0);
                acc2 = __builtin_amdgcn_mfma_f32_16x16x32_bf16(al, bh[2][c], acc2, 0, 0, 0);
                acc3 = __builtin_amdgcn_mfma_f32_16x16x32_bf16(al, bh[3][c], acc3, 0, 0, 0);
            }
        }
#pragma unroll
        for (int r = 0; r < 4; ++r) {
            int row = r0 + kg * 4 + r;
            float dd = dis[row];
            size_t base = (size_t)row * FD;
            HsB[base + 16 * 0 + m] = f2bf(dd * acc0[r]);
            HsB[base + 16 * 1 + m] = f2bf(dd * acc1[r]);
            HsB[base + 16 * 2 + m] = f2bf(dd * acc2[r]);
            HsB[base + 16 * 3 + m] = f2bf(dd * acc3[r]);
        }
    }
}

// ---------- fused: gemm1 (blocks [0,512)) || XCD-partitioned CSR fill ----------
__global__ __launch_bounds__(256) void k_fill_gemm(const int* __restrict__ src,
                                                   const int* __restrict__ dst,
                                                   const int* __restrict__ rp,
                                                   int* __restrict__ cur,
                                                   int* __restrict__ esrc,
                                                   const float* __restrict__ X,
                                                   const float* __restrict__ W,
                                                   const float* __restrict__ dis,
                                                   unsigned short* __restrict__ HsB) {
    __shared__ unsigned short WtHi[4096];
    __shared__ unsigned short WtLo[4096];
    if (blockIdx.x < GEMM_BLOCKS) {
        gemm_body<1>(X, nullptr, W, dis, HsB, WtHi, WtLo, blockIdx.x, GEMM_BLOCKS);
    } else {
        int b  = blockIdx.x - GEMM_BLOCKS;   // GEMM_BLOCKS%8==0 keeps bid&7 alignment
        int g  = b & 7;
        int r  = b >> 3;
        int lo = g * RANGE, hi = lo + RANGE;
        int nthr = (FILL_BLOCKS >> 3) * 256;
        for (int e = r * 256 + threadIdx.x; e < NE; e += nthr) {
            int d = dst[e];
            if (d >= lo && d < hi) {
                int p = rp[d] + atomicAdd(&cur[d], 1);
                esrc[p] = src[e];
            }
        }
    }
}

__global__ __launch_bounds__(256) void k_gemm2(const unsigned short* __restrict__ Ab,
                                               const float* __restrict__ W,
                                               const float* __restrict__ dis,
                                               unsigned short* __restrict__ HsB) {
    __shared__ unsigned short WtHi[4096];
    __shared__ unsigned short WtLo[4096];
    gemm_body<0>(nullptr, Ab, W, dis, HsB, WtHi, WtLo, blockIdx.x, GEMM_BLOCKS);
}

// ---------- gather: one wave per node, lane = feature, 16 loads in flight ----------
// v = dis[d] * (HsB[d,:] + sum_s HsB[s,:]) + bias
// MODE 0: Obf[d,:] = bf16(relu(v))   MODE 1: gmax[batch[d],:] = max(., v)
template<int MODE>
__global__ __launch_bounds__(256) void k_gather(const int* __restrict__ rp,
                                                const int* __restrict__ esrc,
                                                const float* __restrict__ dis,
                                                const unsigned short* __restrict__ HsB,
                                                const float* __restrict__ bias,
                                                unsigned short* __restrict__ Obf,
                                                const int* __restrict__ batch,
                                                unsigned* __restrict__ gmax) {
    int gtid  = blockIdx.x * blockDim.x + threadIdx.x;
    int wave  = gtid >> 6;
    int f     = threadIdx.x & 63;     // feature index
    int nwave = (gridDim.x * blockDim.x) >> 6;
    float bf_ = bias[f];
    for (int d = wave; d < NN; d += nwave) {
        int beg = rp[d], end = rp[d + 1];
        float a0 = bf2f(HsB[(size_t)d * FD + f]);   // self-loop (pre-scaled)
        float a1 = 0.f, a2 = 0.f, a3 = 0.f, a4 = 0.f, a5 = 0.f, a6 = 0.f, a7 = 0.f;
        float a8 = 0.f, a9 = 0.f, aA = 0.f, aB = 0.f, aC = 0.f, aD = 0.f, aE = 0.f, aF = 0.f;
        int j = beg;
#define EDGE(K, ACC) { int s = esrc[j + K]; ACC += bf2f(HsB[(size_t)s * FD + f]); }
        for (; j + 16 <= end; j += 16) {
            EDGE(0, a0)  EDGE(1, a1)  EDGE(2, a2)  EDGE(3, a3)
            EDGE(4, a4)  EDGE(5, a5)  EDGE(6, a6)  EDGE(7, a7)
            EDGE(8, a8)  EDGE(9, a9)  EDGE(10, aA) EDGE(11, aB)
            EDGE(12, aC) EDGE(13, aD) EDGE(14, aE) EDGE(15, aF)
        }
        if (j + 8 <= end) {
            EDGE(0, a0) EDGE(1, a1) EDGE(2, a2) EDGE(3, a3)
            EDGE(4, a4) EDGE(5, a5) EDGE(6, a6) EDGE(7, a7)
            j += 8;
        }
        if (j + 4 <= end) {
            EDGE(0, a8) EDGE(1, a9) EDGE(2, aA) EDGE(3, aB)
            j += 4;
        }
        for (; j < end; ++j) EDGE(0, aC)
#undef EDGE
        float s0 = ((a0 + a1) + (a2 + a3)) + ((a4 + a5) + (a6 + a7));
        float s1 = ((a8 + a9) + (aA + aB)) + ((aC + aD) + (aE + aF));
        float v = fmaf(dis[d], s0 + s1, bf_);
        if (MODE == 0) {
            Obf[(size_t)d * FD + f] = f2bf(fmaxf(v, 0.0f));
        } else {
            atomicMax(&gmax[batch[d] * FD + f], encf(v));
        }
    }
}

// ---------- final: out[g,c] = sum_f gmax[g,f] * Wlin[f,c] + blin[c] ----------
__global__ __launch_bounds__(128) void k_final(const unsigned* __restrict__ gmax,
                                               const float* __restrict__ Wlin,
                                               const float* __restrict__ blin,
                                               float* __restrict__ out) {
    __shared__ float G[NG * FD];
    for (int i = threadIdx.x; i < NG * FD; i += 128) G[i] = decf(gmax[i]);
    __syncthreads();
    int t = threadIdx.x;
    int g = t >> 1, c = t & 1;
    float acc = blin[c];
#pragma unroll
    for (int f = 0; f < 64; ++f) acc = fmaf(G[g * 64 + f], Wlin[f * 2 + c], acc);
    out[g * 2 + c] = acc;
}

extern "C" void kernel_launch(void* const* d_in, const int* in_sizes, int n_in,
                              void* d_out, int out_size, void* d_ws, size_t ws_size,
                              hipStream_t stream) {
    const float* x     = (const float*)d_in[0];
    const int*   eidx  = (const int*)d_in[1];
    const int*   batch = (const int*)d_in[2];
    const float* W1    = (const float*)d_in[3];
    const float* b1    = (const float*)d_in[4];
    const float* W2    = (const float*)d_in[5];
    const float* b2    = (const float*)d_in[6];
    const float* Wlin  = (const float*)d_in[7];
    const float* blin  = (const float*)d_in[8];
    float* out = (float*)d_out;

    const int* src = eidx;
    const int* dst = eidx + NE;

    char* ws = (char*)d_ws;
    size_t off = 0;
    auto alloc = [&](size_t bytes) { char* p = ws + off; off += (bytes + 255) & ~size_t(255); return p; };
    int*            cnt  = (int*)alloc(NN * 4);
    float*          dis  = (float*)alloc(NN * 4);
    int*            rp   = (int*)alloc((NN + 1) * 4);
    int*            bsum = (int*)alloc(NBLK * 4);
    int*            esrc = (int*)alloc(NE * 4);                          // 3.2 MB
    unsigned*       gmax = (unsigned*)alloc(NG * FD * 4);
    unsigned short* HsB  = (unsigned short*)alloc((size_t)NN * FD * 2);  // 6.4 MB
    unsigned short* Obf  = (unsigned short*)alloc((size_t)NN * FD * 2);  // 6.4 MB

    const int B = 256;
    const int gN = (NN + B - 1) / B;
    const int gatherBlocks = 2048;   // 8192 waves, ~6 nodes each

    // ---- CSR build + norm ----
    k_init<<<gN, B, 0, stream>>>(cnt, gmax);
    k_cnt_p<<<1024, B, 0, stream>>>(dst, cnt);
    k_scan1<<<NBLK, SCAN_B, 0, stream>>>(cnt, rp, bsum, dis);
    k_scan23<<<NBLK, 256, 0, stream>>>(rp, bsum, cnt);

    // ---- fill || layer-1 GEMM (independent) ----
    k_fill_gemm<<<GEMM_BLOCKS + FILL_BLOCKS, B, 0, stream>>>(src, dst, rp, cnt, esrc,
                                                             x, W1, dis, HsB);

    // ---- layer 1 gather: Obf = bf16(relu(dis*gather(HsB) + b1)) ----
    k_gather<0><<<gatherBlocks, B, 0, stream>>>(rp, esrc, dis, HsB, b1, Obf, batch, gmax);

    // ---- layer 2: HsB = bf16(dis * (Obf @ W2)) ; gmax = segmax(...) ----
    k_gemm2<<<GEMM_BLOCKS, B, 0, stream>>>(Obf, W2, dis, HsB);
    k_gather<1><<<gatherBlocks, B, 0, stream>>>(rp, esrc, dis, HsB, b2, nullptr, batch, gmax);

    // ---- head ----
    k_final<<<1, 128, 0, stream>>>(gmax, Wlin, blin, out);
}

// Round 10
// 184.676 us; speedup vs baseline: 2.1186x; 1.2014x over previous
//
#include <hip/hip_runtime.h>
#include <float.h>

#define NN 50000
#define NE 800000
#define FD 64
#define NG 64
#define SCAN_B 256
#define NBLK ((NN + SCAN_B - 1) / SCAN_B)   // 196
#define GEMM_BLOCKS 512
#define FILL_BLOCKS 1024
#define RANGE (NN / 8)                      // 6250 dst nodes per assumed-XCD group
#define NEPAD (NE + 8 * NN)                 // padded-CSR worst case: 1.2M entries

typedef __attribute__((ext_vector_type(8))) short short8;
typedef __attribute__((ext_vector_type(8))) float float8;
typedef __attribute__((ext_vector_type(4))) float f32x4;

// ---------- bf16 helpers (RNE) ----------
__device__ inline unsigned short f2bf(float f) {
    unsigned u = __float_as_uint(f);
    u += 0x7fffu + ((u >> 16) & 1u);
    return (unsigned short)(u >> 16);
}
__device__ inline float bf2f(unsigned short h) {
    return __uint_as_float(((unsigned)h) << 16);
}

// ---------- monotonic float<->uint encoding for atomic max ----------
__device__ inline unsigned encf(float f) {
    unsigned u = __float_as_uint(f);
    return (u & 0x80000000u) ? ~u : (u | 0x80000000u);
}
__device__ inline float decf(unsigned e) {
    unsigned u = (e & 0x80000000u) ? (e ^ 0x80000000u) : ~e;
    return __uint_as_float(u);
}

// ---------- init: cnt=0, gmax=enc(-inf), esrc=NN (pad dummy), HsB row NN = 0 ----------
__global__ void k_init(int* __restrict__ cnt, unsigned* __restrict__ gmax,
                       int* __restrict__ esrc, unsigned* __restrict__ zrow) {
    int i = blockIdx.x * blockDim.x + threadIdx.x;
    if (i < NN) cnt[i] = 0;
    if (i < NG * FD) gmax[i] = encf(-FLT_MAX);
    if (i < NEPAD) esrc[i] = NN;              // dummy src -> zero row
    if (i < 32) zrow[i] = 0;                  // HsB row NN (128 B) = 0.0bf16
}

// ---------- histogram, dst-range partitioned by assumed XCD (bid&7) ----------
__global__ __launch_bounds__(256) void k_cnt_p(const int* __restrict__ dst,
                                               int* __restrict__ cnt) {
    int g  = blockIdx.x & 7;
    int r  = blockIdx.x >> 3;
    int lo = g * RANGE, hi = lo + RANGE;
    int nthr = ((int)gridDim.x >> 3) * 256;
    for (int e = r * 256 + threadIdx.x; e < NE; e += nthr) {
        int d = dst[e];
        if (d >= lo && d < hi) atomicAdd(&cnt[d], 1);
    }
}

// ---------- scan1 over PADDED counts (+ dis from real counts) ----------
__global__ void k_scan1(const int* __restrict__ cnt, int* __restrict__ rp,
                        int* __restrict__ bsum, float* __restrict__ dis) {
    __shared__ int tmp[SCAN_B];
    int b = blockIdx.x, t = threadIdx.x;
    int i = b * SCAN_B + t;
    int v  = (i < NN) ? cnt[i] : 0;
    int vp = (v + 7) & ~7;                    // padded to multiple of 8
    if (i < NN) dis[i] = rsqrtf((float)v + 1.0f);   // +1 self loop
    tmp[t] = vp;
    __syncthreads();
    for (int off = 1; off < SCAN_B; off <<= 1) {
        int add = (t >= off) ? tmp[t - off] : 0;
        __syncthreads();
        tmp[t] += add;
        __syncthreads();
    }
    if (i < NN) rp[i] = tmp[t] - vp;
    if (t == SCAN_B - 1) bsum[b] = tmp[t];
}

// ---------- fused scan2+scan3 ----------
__global__ __launch_bounds__(256) void k_scan23(int* __restrict__ rp,
                                                const int* __restrict__ bsum,
                                                int* __restrict__ cnt) {
    __shared__ int ws[4];
    int b = blockIdx.x, t = threadIdx.x;
    int v = (t < b) ? bsum[t] : 0;            // t < b <= 195 -> in bounds
#pragma unroll
    for (int m = 1; m < 64; m <<= 1) v += __shfl_xor(v, m);
    if ((t & 63) == 0) ws[t >> 6] = v;
    __syncthreads();
    int pre = ws[0] + ws[1] + ws[2] + ws[3];
    int i = b * 256 + t;
    if (i < NN) {
        rp[i] += pre;
        cnt[i] = 0;                           // becomes fill cursor
    }
    if (b == NBLK - 1 && t == 0) rp[NN] = pre + bsum[NBLK - 1];
}

// ---------- MFMA GEMM body: HsB[r,:] = bf16( dis[r] * (A[r,:] @ W) ) ----------
template<int SPLIT_A>
__device__ __forceinline__ void gemm_body(const float* __restrict__ Af,
                                          const unsigned short* __restrict__ Ab,
                                          const float* __restrict__ W,
                                          const float* __restrict__ dis,
                                          unsigned short* __restrict__ HsB,
                                          unsigned short* WtHi, unsigned short* WtLo,
                                          int bid, int nblk) {
    for (int i = threadIdx.x; i < 4096; i += 256) {
        int k = i >> 6, n = i & 63;
        float w = W[i];                        // W[k][n]
        unsigned short hi = f2bf(w);
        WtHi[n * 64 + k] = hi;
        WtLo[n * 64 + k] = f2bf(w - bf2f(hi));
    }
    __syncthreads();
    int lane = threadIdx.x & 63;
    int m  = lane & 15;    // A-row / D-col
    int kg = lane >> 4;    // k group
    short8 bh[4][2], bl[4][2];
#pragma unroll
    for (int t = 0; t < 4; ++t)
#pragma unroll
        for (int c = 0; c < 2; ++c) {
            int n  = 16 * t + m;
            int k0 = 32 * c + kg * 8;
            bh[t][c] = *(const short8*)&WtHi[n * 64 + k0];
            bl[t][c] = *(const short8*)&WtLo[n * 64 + k0];
        }
    int wid = (bid * 256 + (int)threadIdx.x) >> 6;
    int nw  = nblk * 4;
    for (int tile = wid; tile < NN / 16; tile += nw) {   // NN = 16*3125 exactly
        int r0 = tile * 16;
        f32x4 z = {0.f, 0.f, 0.f, 0.f};
        f32x4 acc0 = z, acc1 = z, acc2 = z, acc3 = z;
#pragma unroll
        for (int c = 0; c < 2; ++c) {
            short8 ah, al;
            if (SPLIT_A) {
                float8 xv = *(const float8*)(Af + (size_t)(r0 + m) * FD + 32 * c + kg * 8);
#pragma unroll
                for (int j = 0; j < 8; ++j) {
                    unsigned short hi = f2bf(xv[j]);
                    ah[j] = (short)hi;
                    al[j] = (short)f2bf(xv[j] - bf2f(hi));
                }
            } else {
                ah = *(const short8*)(Ab + (size_t)(r0 + m) * FD + 32 * c + kg * 8);
            }
            acc0 = __builtin_amdgcn_mfma_f32_16x16x32_bf16(ah, bh[0][c], acc0, 0, 0, 0);
            acc0 = __builtin_amdgcn_mfma_f32_16x16x32_bf16(ah, bl[0][c], acc0, 0, 0, 0);
            acc1 = __builtin_amdgcn_mfma_f32_16x16x32_bf16(ah, bh[1][c], acc1, 0, 0, 0);
            acc1 = __builtin_amdgcn_mfma_f32_16x16x32_bf16(ah, bl[1][c], acc1, 0, 0, 0);
            acc2 = __builtin_amdgcn_mfma_f32_16x16x32_bf16(ah, bh[2][c], acc2, 0, 0, 0);
            acc2 = __builtin_amdgcn_mfma_f32_16x16x32_bf16(ah, bl[2][c], acc2, 0, 0, 0);
            acc3 = __builtin_amdgcn_mfma_f32_16x16x32_bf16(ah, bh[3][c], acc3, 0, 0, 0);
            acc3 = __builtin_amdgcn_mfma_f32_16x16x32_bf16(ah, bl[3][c], acc3, 0, 0, 0);
            if (SPLIT_A) {
                acc0 = __builtin_amdgcn_mfma_f32_16x16x32_bf16(al, bh[0][c], acc0, 0, 0, 0);
                acc1 = __builtin_amdgcn_mfma_f32_16x16x32_bf16(al, bh[1][c], acc1, 0, 0, 0);
                acc2 = __builtin_amdgcn_mfma_f32_16x16x32_bf16(al, bh[2][c], acc2, 0, 0, 0);
                acc3 = __builtin_amdgcn_mfma_f32_16x16x32_bf16(al, bh[3][c], acc3, 0, 0, 0);
            }
        }
#pragma unroll
        for (int r = 0; r < 4; ++r) {
            int row = r0 + kg * 4 + r;
            float dd = dis[row];
            size_t base = (size_t)row * FD;
            HsB[base + 16 * 0 + m] = f2bf(dd * acc0[r]);
            HsB[base + 16 * 1 + m] = f2bf(dd * acc1[r]);
            HsB[base + 16 * 2 + m] = f2bf(dd * acc2[r]);
            HsB[base + 16 * 3 + m] = f2bf(dd * acc3[r]);
        }
    }
}

// ---------- fused: gemm1 (blocks [0,512)) || XCD-partitioned CSR fill ----------
__global__ __launch_bounds__(256) void k_fill_gemm(const int* __restrict__ src,
                                                   const int* __restrict__ dst,
                                                   const int* __restrict__ rp,
                                                   int* __restrict__ cur,
                                                   int* __restrict__ esrc,
                                                   const float* __restrict__ X,
                                                   const float* __restrict__ W,
                                                   const float* __restrict__ dis,
                                                   unsigned short* __restrict__ HsB) {
    __shared__ unsigned short WtHi[4096];
    __shared__ unsigned short WtLo[4096];
    if (blockIdx.x < GEMM_BLOCKS) {
        gemm_body<1>(X, nullptr, W, dis, HsB, WtHi, WtLo, blockIdx.x, GEMM_BLOCKS);
    } else {
        int b  = blockIdx.x - GEMM_BLOCKS;   // GEMM_BLOCKS%8==0 keeps bid&7 alignment
        int g  = b & 7;
        int r  = b >> 3;
        int lo = g * RANGE, hi = lo + RANGE;
        int nthr = (FILL_BLOCKS >> 3) * 256;
        for (int e = r * 256 + threadIdx.x; e < NE; e += nthr) {
            int d = dst[e];
            if (d >= lo && d < hi) {
                int p = rp[d] + atomicAdd(&cur[d], 1);
                esrc[p] = src[e];
            }
        }
    }
}

__global__ __launch_bounds__(256) void k_gemm2(const unsigned short* __restrict__ Ab,
                                               const float* __restrict__ W,
                                               const float* __restrict__ dis,
                                               unsigned short* __restrict__ HsB) {
    __shared__ unsigned short WtHi[4096];
    __shared__ unsigned short WtLo[4096];
    gemm_body<0>(nullptr, Ab, W, dis, HsB, WtHi, WtLo, blockIdx.x, GEMM_BLOCKS);
}

// ---------- gather: one wave per node, 8 rows per instruction ----------
// Padded CSR: every segment length % 8 == 0; pad entries point at zero row NN.
// slot = lane>>3 (edge within group of 8), fg = lane&7 (16 B slice of row).
// Lanes 0-7 read one contiguous 128 B row -> 8 rows per wave instruction.
// After the loop: butterfly-sum over slots, add self row, scale, bias.
// MODE 0: Obf[d,:] = bf16(relu(v))   MODE 1: gmax[batch[d],:] = max(., v)
template<int MODE>
__global__ __launch_bounds__(256) void k_gather8(const int* __restrict__ rp,
                                                 const int* __restrict__ esrc,
                                                 const float* __restrict__ dis,
                                                 const unsigned short* __restrict__ HsB,
                                                 const float* __restrict__ bias,
                                                 unsigned short* __restrict__ Obf,
                                                 const int* __restrict__ batch,
                                                 unsigned* __restrict__ gmax) {
    int gtid  = blockIdx.x * blockDim.x + threadIdx.x;
    int wave  = gtid >> 6;
    int lane  = threadIdx.x & 63;
    int slot  = lane >> 3;     // edge slot 0..7
    int fg    = lane & 7;      // 16 B slice: feats [fg*8, fg*8+8)
    int nwave = (gridDim.x * blockDim.x) >> 6;
    float bb0, bb1, bb2, bb3, bb4, bb5, bb6, bb7, bbp;
    if (MODE == 0) {
        bb0 = bias[fg * 8 + 0]; bb1 = bias[fg * 8 + 1];
        bb2 = bias[fg * 8 + 2]; bb3 = bias[fg * 8 + 3];
        bb4 = bias[fg * 8 + 4]; bb5 = bias[fg * 8 + 5];
        bb6 = bias[fg * 8 + 6]; bb7 = bias[fg * 8 + 7];
    } else {
        bbp = bias[fg * 8 + slot];
    }
    for (int d = wave; d < NN; d += nwave) {
        int beg = rp[d], end = rp[d + 1];      // multiples of 8
        float b0 = 0.f, b1 = 0.f, b2 = 0.f, b3 = 0.f;
        float b4 = 0.f, b5 = 0.f, b6 = 0.f, b7 = 0.f;
        int j = beg;
        for (; j + 16 <= end; j += 16) {       // 2 independent idx->row chains
            int s0 = esrc[j + slot];
            int s1 = esrc[j + 8 + slot];
            short8 r0 = *(const short8*)(HsB + (size_t)s0 * FD + fg * 8);
            short8 r1 = *(const short8*)(HsB + (size_t)s1 * FD + fg * 8);
            b0 += bf2f((unsigned short)r0[0]) + bf2f((unsigned short)r1[0]);
            b1 += bf2f((unsigned short)r0[1]) + bf2f((unsigned short)r1[1]);
            b2 += bf2f((unsigned short)r0[2]) + bf2f((unsigned short)r1[2]);
            b3 += bf2f((unsigned short)r0[3]) + bf2f((unsigned short)r1[3]);
            b4 += bf2f((unsigned short)r0[4]) + bf2f((unsigned short)r1[4]);
            b5 += bf2f((unsigned short)r0[5]) + bf2f((unsigned short)r1[5]);
            b6 += bf2f((unsigned short)r0[6]) + bf2f((unsigned short)r1[6]);
            b7 += bf2f((unsigned short)r0[7]) + bf2f((unsigned short)r1[7]);
        }
        if (j < end) {                          // single remaining group of 8
            int s0 = esrc[j + slot];
            short8 r0 = *(const short8*)(HsB + (size_t)s0 * FD + fg * 8);
            b0 += bf2f((unsigned short)r0[0]);
            b1 += bf2f((unsigned short)r0[1]);
            b2 += bf2f((unsigned short)r0[2]);
            b3 += bf2f((unsigned short)r0[3]);
            b4 += bf2f((unsigned short)r0[4]);
            b5 += bf2f((unsigned short)r0[5]);
            b6 += bf2f((unsigned short)r0[6]);
            b7 += bf2f((unsigned short)r0[7]);
        }
#define RED(MSK) b0 += __shfl_xor(b0, MSK); b1 += __shfl_xor(b1, MSK); \
                 b2 += __shfl_xor(b2, MSK); b3 += __shfl_xor(b3, MSK); \
                 b4 += __shfl_xor(b4, MSK); b5 += __shfl_xor(b5, MSK); \
                 b6 += __shfl_xor(b6, MSK); b7 += __shfl_xor(b7, MSK);
        RED(8) RED(16) RED(32)
#undef RED
        float dd = dis[d];
        if (MODE == 0) {
            const short8 rs = *(const short8*)(HsB + (size_t)d * FD + fg * 8);
            if (slot == 0) {
                short8 o;
                o[0] = (short)f2bf(fmaxf(fmaf(dd, b0 + bf2f((unsigned short)rs[0]), bb0), 0.f));
                o[1] = (short)f2bf(fmaxf(fmaf(dd, b1 + bf2f((unsigned short)rs[1]), bb1), 0.f));
                o[2] = (short)f2bf(fmaxf(fmaf(dd, b2 + bf2f((unsigned short)rs[2]), bb2), 0.f));
                o[3] = (short)f2bf(fmaxf(fmaf(dd, b3 + bf2f((unsigned short)rs[3]), bb3), 0.f));
                o[4] = (short)f2bf(fmaxf(fmaf(dd, b4 + bf2f((unsigned short)rs[4]), bb4), 0.f));
                o[5] = (short)f2bf(fmaxf(fmaf(dd, b5 + bf2f((unsigned short)rs[5]), bb5), 0.f));
                o[6] = (short)f2bf(fmaxf(fmaf(dd, b6 + bf2f((unsigned short)rs[6]), bb6), 0.f));
                o[7] = (short)f2bf(fmaxf(fmaf(dd, b7 + bf2f((unsigned short)rs[7]), bb7), 0.f));
                *(short8*)(Obf + (size_t)d * FD + fg * 8) = o;
            }
        } else {
            // lane covers feature fg*8 + slot: pick b[slot], scalar self load
            float pk = b0;
            pk = (slot == 1) ? b1 : pk;
            pk = (slot == 2) ? b2 : pk;
            pk = (slot == 3) ? b3 : pk;
            pk = (slot == 4) ? b4 : pk;
            pk = (slot == 5) ? b5 : pk;
            pk = (slot == 6) ? b6 : pk;
            pk = (slot == 7) ? b7 : pk;
            float sv = bf2f(HsB[(size_t)d * FD + fg * 8 + slot]);
            float v = fmaf(dd, pk + sv, bbp);
            atomicMax(&gmax[batch[d] * FD + fg * 8 + slot], encf(v));
        }
    }
}

// ---------- final: out[g,c] = sum_f gmax[g,f] * Wlin[f,c] + blin[c] ----------
__global__ __launch_bounds__(128) void k_final(const unsigned* __restrict__ gmax,
                                               const float* __restrict__ Wlin,
                                               const float* __restrict__ blin,
                                               float* __restrict__ out) {
    __shared__ float G[NG * FD];
    for (int i = threadIdx.x; i < NG * FD; i += 128) G[i] = decf(gmax[i]);
    __syncthreads();
    int t = threadIdx.x;
    int g = t >> 1, c = t & 1;
    float acc = blin[c];
#pragma unroll
    for (int f = 0; f < 64; ++f) acc = fmaf(G[g * 64 + f], Wlin[f * 2 + c], acc);
    out[g * 2 + c] = acc;
}

extern "C" void kernel_launch(void* const* d_in, const int* in_sizes, int n_in,
                              void* d_out, int out_size, void* d_ws, size_t ws_size,
                              hipStream_t stream) {
    const float* x     = (const float*)d_in[0];
    const int*   eidx  = (const int*)d_in[1];
    const int*   batch = (const int*)d_in[2];
    const float* W1    = (const float*)d_in[3];
    const float* b1    = (const float*)d_in[4];
    const float* W2    = (const float*)d_in[5];
    const float* b2    = (const float*)d_in[6];
    const float* Wlin  = (const float*)d_in[7];
    const float* blin  = (const float*)d_in[8];
    float* out = (float*)d_out;

    const int* src = eidx;
    const int* dst = eidx + NE;

    char* ws = (char*)d_ws;
    size_t off = 0;
    auto alloc = [&](size_t bytes) { char* p = ws + off; off += (bytes + 255) & ~size_t(255); return p; };
    int*            cnt  = (int*)alloc(NN * 4);
    float*          dis  = (float*)alloc(NN * 4);
    int*            rp   = (int*)alloc((NN + 1) * 4);
    int*            bsum = (int*)alloc(NBLK * 4);
    int*            esrc = (int*)alloc((size_t)NEPAD * 4);               // 4.8 MB
    unsigned*       gmax = (unsigned*)alloc(NG * FD * 4);
    unsigned short* HsB  = (unsigned short*)alloc((size_t)(NN + 1) * FD * 2);  // +zero row
    unsigned short* Obf  = (unsigned short*)alloc((size_t)NN * FD * 2);

    const int B = 256;
    const int gInit = (NEPAD + B - 1) / B;    // covers esrc prefill + all init work
    const int gatherBlocks = 2048;            // 8192 waves, ~6 nodes each

    // ---- init + CSR build (padded) + norm ----
    k_init<<<gInit, B, 0, stream>>>(cnt, gmax, esrc, (unsigned*)(HsB + (size_t)NN * FD));
    k_cnt_p<<<1024, B, 0, stream>>>(dst, cnt);
    k_scan1<<<NBLK, SCAN_B, 0, stream>>>(cnt, rp, bsum, dis);
    k_scan23<<<NBLK, 256, 0, stream>>>(rp, bsum, cnt);

    // ---- fill || layer-1 GEMM (independent) ----
    k_fill_gemm<<<GEMM_BLOCKS + FILL_BLOCKS, B, 0, stream>>>(src, dst, rp, cnt, esrc,
                                                             x, W1, dis, HsB);

    // ---- layer 1 gather: Obf = bf16(relu(dis*gather(HsB) + b1)) ----
    k_gather8<0><<<gatherBlocks, B, 0, stream>>>(rp, esrc, dis, HsB, b1, Obf, batch, gmax);

    // ---- layer 2: HsB = bf16(dis * (Obf @ W2)) ; gmax = segmax(...) ----
    k_gemm2<<<GEMM_BLOCKS, B, 0, stream>>>(Obf, W2, dis, HsB);
    k_gather8<1><<<gatherBlocks, B, 0, stream>>>(rp, esrc, dis, HsB, b2, nullptr, batch, gmax);

    // ---- head ----
    k_final<<<1, 128, 0, stream>>>(gmax, Wlin, blin, out);
}